// Round 1
// 525.121 us; speedup vs baseline: 1.2545x; 1.2545x over previous
//
#include <hip/hip_runtime.h>

// FFT long conv: out[b,d,l] = (1/16384^2 forward-norm pair) * linear conv of x,f, masked.
// One workgroup per (b,d) channel; complex FFT 8192 in 64KB LDS.
//
// R2 restructure vs the 657µs baseline:
//  * radix-8-style merged passes: 13 radix-2 stages -> 4 register passes of 3 stages
//    (bits {12..10},{9..7},{6..4},{3..1}) + the bit-0 stage via __shfl_xor (no LDS).
//    LDS round trips per FFT: 13 -> 4. Barriers: ~58 -> 19.
//  * one __sincosf per pass (stage twiddles are T1, T1^2, T1^4 x constant 8th roots)
//    instead of one per butterfly: ~220 -> ~18 sincos/thread.
//  * LDS XOR swizzle  i ^ (((i>>4)&7)<<1)  -> bank-conflict-free passes; hoisted to
//    ~zero extra VALU via known-zero-bit identities (verified numerically below).
//  * pointwise iterates bit-reversed addresses p1=2e (even addr <=> freq j<4096, so each
//    hermitian pair hit exactly once); partner = rev13(8192-j) (even spec) / 8191-p1 (odd).
//    Coalesced, replaces the 32-way-conflicted rev13-scatter.
//  * __launch_bounds__(1024,4): allow 128 VGPRs, eliminate scratch spills (suspected
//    source of the 485MB of extra HBM traffic in the baseline counters).
//
// positions arrives as int32 from the harness (int64 in the npz) - keep const int*.

#define N_FFT 8192
#define NT    1024
#define NPT   8
#define PI_F  3.14159265358979323846f
#define RS2   0.70710678118654752440f

__device__ __forceinline__ float2 cmul(float2 a, float2 b) {
    return make_float2(a.x * b.x - a.y * b.y, a.x * b.y + a.y * b.x);
}
__device__ __forceinline__ float2 cadd(float2 a, float2 b) { return make_float2(a.x + b.x, a.y + b.y); }
__device__ __forceinline__ float2 csub(float2 a, float2 b) { return make_float2(a.x - b.x, a.y - b.y); }
__device__ __forceinline__ float2 mneg_i(float2 a) { return make_float2(a.y, -a.x); }  // a * (-i)
__device__ __forceinline__ float2 mpos_i(float2 a) { return make_float2(-a.y, a.x); }  // a * (+i)

__device__ __forceinline__ int rev13(int v) { return (int)(__brev((unsigned)v) >> 19); }
// LDS bank swizzle: XOR bits 1..3 with bits 4..6 (float2 units). Bijective within [0,8192).
__device__ __forceinline__ int swz(int i) { return i ^ (((i >> 4) & 7) << 1); }

// Pass ownership: thread t owns elements  base + (k<<B), k=0..7, where
// base = (hi << (B+3)) | lo, lo = t & ((1<<B)-1), hi = t >> B.
// Swizzled-address identities (bits of k<<B never carry into the XOR field):
//   B>=7 : swz(base + (k<<B)) = swz(base) + (k<<B)                (bits4..6 from base)
//   B==4 : swz(base + (k<<4)) = (base ^ (k<<1)) + (k<<4)          ((i>>4)&7 == k)
//   B==1 : swz(base + (k<<1)) = (base ^ mask) ^ (k<<1),           (bits1..3 of base are 0,
//           mask = ((base>>4)&7)<<1                                 (i>>4)&7 == hi&7)
template <int B>
__device__ __forceinline__ int pass_base(int t) {
    const int lo   = t & ((1 << B) - 1);
    const int hi   = t >> B;
    const int base = (hi << (B + 3)) | lo;
    if constexpr (B == 4) return base;
    else                  return base ^ (((base >> 4) & 7) << 1);
}
template <int B>
__device__ __forceinline__ int pass_addr(int sb, int k) {
    if constexpr (B >= 7)      return sb + (k << B);
    else if constexpr (B == 4) return (sb ^ (k << 1)) + (k << 4);
    else                       return sb ^ (k << 1);
}

// ---- forward DIF merged pass: stages B+2, B+1, B (descending), exact composition of
//      the verified radix-2 loop. LAST==true (B==1) appends stage 0 via shfl_xor. ----
template <int B, bool LAST>
__device__ __forceinline__ void fwd_pass(float2* a, int t) {
    const int h  = 1 << B;
    const int lo = t & (h - 1);
    const int sb = pass_base<B>(t);
    float2 r[8];
#pragma unroll
    for (int k = 0; k < 8; ++k) r[k] = a[pass_addr<B>(sb, k)];

    float sn, cs;
    __sincosf(-PI_F * (float)lo / (float)(4 * h), &sn, &cs);
    const float2 T1  = make_float2(cs, sn);                    // e^{-i pi lo/(4h)}
    const float2 T2  = cmul(T1, T1);
    const float2 T4  = cmul(T2, T2);
    const float2 T1b = cmul(T1, make_float2(RS2, -RS2));       // T1 * e^{-i pi/4}

    // stage B+2: pairs (k,k+4), twiddle T1 * e^{-i pi k/4}
#pragma unroll
    for (int k = 0; k < 4; ++k) {
        float2 u = r[k], v = r[k + 4];
        r[k] = cadd(u, v);
        float2 d  = csub(u, v);
        float2 tw = (k == 0) ? T1 : (k == 1) ? T1b : (k == 2) ? mneg_i(T1) : mneg_i(T1b);
        r[k + 4] = cmul(d, tw);
    }
    // stage B+1: pairs (k,k+2), k in {0,1,4,5}, twiddle T2 * (k&1 ? -i : 1)
#pragma unroll
    for (int k0 = 0; k0 < 8; k0 += 4) {
#pragma unroll
        for (int kk = 0; kk < 2; ++kk) {
            const int k = k0 + kk;
            float2 u = r[k], v = r[k + 2];
            r[k] = cadd(u, v);
            r[k + 2] = cmul(csub(u, v), kk ? mneg_i(T2) : T2);
        }
    }
    // stage B: pairs (k,k+1), k even, twiddle T4
#pragma unroll
    for (int k = 0; k < 8; k += 2) {
        float2 u = r[k], v = r[k + 1];
        r[k] = cadd(u, v);
        r[k + 1] = cmul(csub(u, v), T4);
    }
    if (LAST) {  // stage 0 (half=1, twiddle 1): partner is lane t^1, same k
        const float sgn = (t & 1) ? -1.0f : 1.0f;
#pragma unroll
        for (int k = 0; k < 8; ++k) {
            float ox = __shfl_xor(r[k].x, 1);
            float oy = __shfl_xor(r[k].y, 1);
            r[k].x = ox + sgn * r[k].x;
            r[k].y = oy + sgn * r[k].y;
        }
    }
#pragma unroll
    for (int k = 0; k < 8; ++k) a[pass_addr<B>(sb, k)] = r[k];
}

// ---- inverse DIT merged pass: stages B, B+1, B+2 (ascending).
//      FIRST==true (B==1) prepends stage 0 via shfl_xor. STORE==false leaves result in r. ----
template <int B, bool FIRST, bool STORE>
__device__ __forceinline__ void inv_pass(float2* a, int t, float2 r[8]) {
    const int h  = 1 << B;
    const int lo = t & (h - 1);
    const int sb = pass_base<B>(t);
#pragma unroll
    for (int k = 0; k < 8; ++k) r[k] = a[pass_addr<B>(sb, k)];

    if (FIRST) {
        const float sgn = (t & 1) ? -1.0f : 1.0f;
#pragma unroll
        for (int k = 0; k < 8; ++k) {
            float ox = __shfl_xor(r[k].x, 1);
            float oy = __shfl_xor(r[k].y, 1);
            r[k].x = ox + sgn * r[k].x;
            r[k].y = oy + sgn * r[k].y;
        }
    }
    float sn, cs;
    __sincosf(PI_F * (float)lo / (float)(4 * h), &sn, &cs);
    const float2 U1  = make_float2(cs, sn);                    // e^{+i pi lo/(4h)}
    const float2 U2  = cmul(U1, U1);
    const float2 U4  = cmul(U2, U2);
    const float2 U1b = cmul(U1, make_float2(RS2, RS2));        // U1 * e^{+i pi/4}

    // stage B: pairs (k,k+1), k even, v twiddled by U4
#pragma unroll
    for (int k = 0; k < 8; k += 2) {
        float2 u = r[k];
        float2 v = cmul(r[k + 1], U4);
        r[k] = cadd(u, v);
        r[k + 1] = csub(u, v);
    }
    // stage B+1: pairs (k,k+2), k in {0,1,4,5}, twiddle U2 * (k&1 ? +i : 1)
#pragma unroll
    for (int k0 = 0; k0 < 8; k0 += 4) {
#pragma unroll
        for (int kk = 0; kk < 2; ++kk) {
            const int k = k0 + kk;
            float2 u = r[k];
            float2 v = cmul(r[k + 2], kk ? mpos_i(U2) : U2);
            r[k] = cadd(u, v);
            r[k + 2] = csub(u, v);
        }
    }
    // stage B+2: pairs (k,k+4), twiddle U1 * e^{+i pi k/4}
#pragma unroll
    for (int k = 0; k < 4; ++k) {
        float2 tw = (k == 0) ? U1 : (k == 1) ? U1b : (k == 2) ? mpos_i(U1) : mpos_i(U1b);
        float2 u = r[k];
        float2 v = cmul(r[k + 4], tw);
        r[k] = cadd(u, v);
        r[k + 4] = csub(u, v);
    }
    if (STORE) {
#pragma unroll
        for (int k = 0; k < 8; ++k) a[pass_addr<B>(sb, k)] = r[k];
    }
}

// Z1 = W_k, Z2 = W_{N-k} of combined x+i*f spectrum -> Yhat_k = Xhat_k*Fhat_k*scale.
__device__ __forceinline__ float2 pw(float2 z1, float2 z2, float scale) {
    float2 X = make_float2(0.5f * (z1.x + z2.x), 0.5f * (z1.y - z2.y));
    float2 D = make_float2(z1.x - z2.x, z1.y + z2.y);
    float2 F = make_float2(0.5f * D.y, -0.5f * D.x);
    float2 Y = cmul(X, F);
    return make_float2(Y.x * scale, Y.y * scale);
}

__global__ void __launch_bounds__(NT, 4)
fftconv_kernel(const float* __restrict__ x, const float* __restrict__ f,
               const int* __restrict__ pos, float* __restrict__ out) {
    __shared__ float2 a[N_FFT];                 // 64 KiB
    const int t  = threadIdx.x;
    const int c  = blockIdx.x;                  // channel b*256 + d
    const int bb = c >> 8;
    const size_t gbase = (size_t)c * N_FFT;
    const int* pbase = pos + (size_t)bb * N_FFT;

    const float scale = 1.0f / (16384.0f * 16384.0f);  // two forward-norm 1/n factors

    // swz(q*1024 + t) = st + q*1024  (bits 4..6 of m come from t; q*1024 doesn't interfere)
    const int st = t ^ (((t >> 4) & 7) << 1);

    float2 w[NPT];   // stashed packed input (x + i f)
    float  yr[NPT];  // stashed Re(ye)
    float2 r[8];

    // ---- load x,f; pack w = x + i f (natural order) ----
#pragma unroll
    for (int q = 0; q < NPT; ++q) {
        const int m = q * NT + t;
        w[q] = make_float2(x[gbase + m], f[gbase + m]);
        a[st + q * NT] = w[q];
    }
    __syncthreads();

    // ---- even spectrum: FFT_8192(w), bit-reversed order ----
    fwd_pass<10, false>(a, t); __syncthreads();
    fwd_pass<7,  false>(a, t); __syncthreads();
    fwd_pass<4,  false>(a, t); __syncthreads();
    fwd_pass<1,  true >(a, t); __syncthreads();

    // ---- even pointwise, iterated by bit-reversed address p1 = 2e (<=> j < 4096) ----
#pragma unroll
    for (int q = 0; q < 4; ++q) {
        const int e  = q * NT + t;
        const int p1 = 2 * e;
        if (e == 0) {  // j=4096 self-pair lives at odd address 1 (never enumerated below)
            float2 z = a[swz(1)];
            a[swz(1)] = pw(z, z, scale);
        }
        const int j  = rev13(p1);                          // j in [0,4095]
        const int p2 = rev13((N_FFT - j) & (N_FFT - 1));   // partner addr (odd); j=0 -> p2=p1=0, Y real
        float2 z1 = a[swz(p1)];
        float2 z2 = a[swz(p2)];
        float2 Y  = pw(z1, z2, scale);
        a[swz(p1)] = Y;
        a[swz(p2)] = make_float2(Y.x, -Y.y);
    }
    __syncthreads();

    // ---- ye = IDFT(Yhat_even); keep Re in registers (no LDS writeback on last pass) ----
    inv_pass<1,  true,  true >(a, t, r); __syncthreads();
    inv_pass<4,  false, true >(a, t, r); __syncthreads();
    inv_pass<7,  false, true >(a, t, r); __syncthreads();
    inv_pass<10, false, false>(a, t, r);
#pragma unroll
    for (int k = 0; k < 8; ++k) yr[k] = r[k].x;   // r[k] holds element m = k*1024 + t
    __syncthreads();  // all reads of a[] done before odd modulate overwrites

    // ---- odd spectrum input: w * e^{-i pi m / 8192}, m = q*1024 + t ----
    {
        const float CC[8] = {1.0f, 0.92387953f, 0.70710678f, 0.38268343f,
                             0.0f, -0.38268343f, -0.70710678f, -0.92387953f};
        const float SS[8] = {0.0f, 0.38268343f, 0.70710678f, 0.92387953f,
                             1.0f, 0.92387953f, 0.70710678f, 0.38268343f};
        float sn, cs;
        __sincosf(-PI_F * (float)t / 8192.0f, &sn, &cs);
        const float2 Bt = make_float2(cs, sn);
#pragma unroll
        for (int q = 0; q < NPT; ++q) {
            const float2 tw = cmul(Bt, make_float2(CC[q], -SS[q]));  // e^{-i pi (t + 1024q)/8192}
            a[st + q * NT] = cmul(w[q], tw);
        }
    }
    __syncthreads();

    fwd_pass<10, false>(a, t); __syncthreads();
    fwd_pass<7,  false>(a, t); __syncthreads();
    fwd_pass<4,  false>(a, t); __syncthreads();
    fwd_pass<1,  true >(a, t); __syncthreads();

    // ---- odd pointwise: partner of addr p1 is 8191 - p1 (rev13 of complement) ----
#pragma unroll
    for (int q = 0; q < 4; ++q) {
        const int e  = q * NT + t;
        const int p1 = 2 * e;
        const int p2 = N_FFT - 1 - p1;
        float2 z1 = a[swz(p1)];
        float2 z2 = a[swz(p2)];
        float2 Y  = pw(z1, z2, scale);
        a[swz(p1)] = Y;
        a[swz(p2)] = make_float2(Y.x, -Y.y);
    }
    __syncthreads();

    // ---- yo = IDFT(Yhat_odd), result in registers ----
    inv_pass<1,  true,  true >(a, t, r); __syncthreads();
    inv_pass<4,  false, true >(a, t, r); __syncthreads();
    inv_pass<7,  false, true >(a, t, r); __syncthreads();
    inv_pass<10, false, false>(a, t, r);

    // ---- combine y_m = Re(ye) + Re(e^{+i pi m/8192} * yo), mask, store ----
    {
        const float CC[8] = {1.0f, 0.92387953f, 0.70710678f, 0.38268343f,
                             0.0f, -0.38268343f, -0.70710678f, -0.92387953f};
        const float SS[8] = {0.0f, 0.38268343f, 0.70710678f, 0.92387953f,
                             1.0f, 0.92387953f, 0.70710678f, 0.38268343f};
        float sn, cs;
        __sincosf(PI_F * (float)t / 8192.0f, &sn, &cs);
        const float2 Bt = make_float2(cs, sn);
#pragma unroll
        for (int q = 0; q < NPT; ++q) {
            const int m = q * NT + t;
            const float2 tw = cmul(Bt, make_float2(CC[q], SS[q]));   // e^{+i pi m/8192}
            const float val = yr[q] + tw.x * r[q].x - tw.y * r[q].y;
            const float msk = (pbase[m] != -1) ? 1.0f : 0.0f;
            out[gbase + m] = val * msk;
        }
    }
}

extern "C" void kernel_launch(void* const* d_in, const int* in_sizes, int n_in,
                              void* d_out, int out_size, void* d_ws, size_t ws_size,
                              hipStream_t stream) {
    const float* x   = (const float*)d_in[0];
    const float* f   = (const float*)d_in[1];
    const int*   pos = (const int*)d_in[2];
    float*       out = (float*)d_out;
    (void)in_sizes; (void)n_in; (void)out_size; (void)d_ws; (void)ws_size;

    // B*D = 8*256 = 2048 channels, one block each
    fftconv_kernel<<<2048, NT, 0, stream>>>(x, f, pos, out);
}